// Round 18
// baseline (173.855 us; speedup 1.0000x reference)
//
#include <hip/hip_runtime.h>
#include <stdint.h>

#define BATCH   2048
#define KDIM    4096
#define NDIM    11008

#define BM 128
#define BN 128
#define BK 128
#define NT (KDIM / BK)               // 32 K-tiles

// LDS: A double-buffer only (B lives in registers). 2x16KB + pad -> 41KB
// so at most 3 blocks/CU (160KB/41KB = 3.9); 12 waves/CU.
#define A0_OFF 0
#define A1_OFF 16384

typedef __attribute__((ext_vector_type(4))) int i32x4;

typedef const __attribute__((address_space(1))) char glob_char;
typedef __attribute__((address_space(3))) char lds_char;

__device__ __forceinline__ unsigned pack4(i32x4 v) {
  return  ((unsigned)v.x & 0xFFu)
        | (((unsigned)v.y & 0xFFu) << 8)
        | (((unsigned)v.z & 0xFFu) << 16)
        | (((unsigned)v.w)         << 24);
}

// A: int32 (values in [-128,127]) -> packed int8, 4 elements per thread
__global__ __launch_bounds__(256) void convert_i32_i8(const int* __restrict__ src,
                                                      unsigned* __restrict__ dst,
                                                      int n4) {
  int idx = blockIdx.x * 256 + threadIdx.x;
  if (idx >= n4) return;
  i32x4 v = ((const i32x4*)src)[idx];
  dst[idx] = pack4(v);
}

// B: ternary int32 -> 2-bit packed, KT-TILED layout for direct reg loads:
//   B3[nt 86][kt 32][row-in-tile 128][8 words], word j covers k=j*16..+16
//   (element e of a word at bits [8*(e&3) + 2*(e>>2)], R12-R17-validated).
// No bank swizzle needed: B never touches LDS.
__global__ __launch_bounds__(256) void convert_w2(const int* __restrict__ src,
                                                  unsigned* __restrict__ dst) {
  const int f = blockIdx.x * 256 + threadIdx.x;   // < 11008*256
  const int r = f >> 8;                           // row 0..11007
  const int i = f & 255;                          // word-in-row (k-order)
  const int* p = src + (size_t)r * KDIM + i * 16;
  unsigned w = 0;
#pragma unroll
  for (int e = 0; e < 16; ++e) {
    const unsigned v = (unsigned)p[e] & 3u;       // -1->3, 0->0, 1->1
    w |= v << (8 * (e & 3) + 2 * (e >> 2));
  }
  const int ntq   = r >> 7;                       // 128-row tile
  const int rowin = r & 127;
  const int kt    = i >> 3;                       // 8 words per KT128
  const int j     = i & 7;
  dst[(size_t)ntq * 32768 + kt * 1024 + rowin * 8 + j] = w;
}

// decode 16x 2-bit ternary -> 16 int8 (k-order): (x&M1) | ((y<<7)-y), y=x&M2
__device__ __forceinline__ i32x4 dec2(unsigned w) {
  const unsigned M1 = 0x01010101u, M2 = 0x02020202u;
  i32x4 r;
  { unsigned x = w;      unsigned y = x & M2; r.x = (int)((x & M1) | ((y << 7) - y)); }
  { unsigned x = w >> 2; unsigned y = x & M2; r.y = (int)((x & M1) | ((y << 7) - y)); }
  { unsigned x = w >> 4; unsigned y = x & M2; r.z = (int)((x & M1) | ((y << 7) - y)); }
  { unsigned x = w >> 6; unsigned y = x & M2; r.w = (int)((x & M1) | ((y << 7) - y)); }
  return r;
}

// C[2048][11008] = A[2048][4096] * W[11008][4096]^T via mfma_i32_16x16x64_i8.
// R19 = R14 minus B-in-LDS (B direct global->register, per-wave-unique):
//  - LDS-port relief: R14's per-CU-KT LDS load (~83% busy: 192 b128 reads +
//    48 b32 B-reads + 24KB staging writes) loses all B traffic; bank
//    conflicts (from B b32) -> ~0.
//  - B per wave per KT = 4 words (n{0,1} x ks{0,1}), one global_load_dword
//    each from the KT-tiled B3 layout; prefetch DEPTH-2 into named regs,
//    reloaded right after dec2 consumes them (WAR keeps order; rule-20
//    static names, x2-unrolled loop).
//  - vmcnt: per KT issue {A(t+1)x4 gload_lds, B(t+2)x4 reg-load};
//    vmcnt(4) retires the 8 oldest = {B(t+1)x4, A(t+1)x4}, leaves B(t+2)
//    in flight. ONE barrier per KT (A dbuf, R7-validated skeleton).
//  - Geometry = R14: G=16x86=1376 (89.6% tail), 4 waves 1m x 4n, wave
//    128x32, acc[8][2]=64 AGPR (~140 unified regs: >128 blocks a 4th
//    block, <=170 keeps 3/SIMD); 41KB LDS pins 3 blocks/CU.
//  - A slot-swizzle on global source + XCD/supertile raster: unchanged.
__global__ __launch_bounds__(256, 3) void ternary_gemm(const char* __restrict__ A8,
                                                       const unsigned* __restrict__ B3,
                                                       const float* __restrict__ scale,
                                                       const float* __restrict__ bias,
                                                       float* __restrict__ out) {
  __shared__ char lds[41088];          // A dbuf 32KB + pad -> 3 blocks/CU

  const int tid  = threadIdx.x;
  const int wid  = tid >> 6;
  const int lane = tid & 63;

  // XCD swizzle (1376 % 8 == 0 -> bijective) + 4-wide mt-supertile raster
  const int wg  = (blockIdx.x & 7) * 172 + (blockIdx.x >> 3);
  const int mtq = wg / 344;
  const int r   = wg - mtq * 344;
  const int nt  = r >> 2;               // 0..85
  const int mt  = mtq * 4 + (r & 3);    // 0..15
  const int arow0 = mt * BM;
  const int brow0 = nt * BN;

  const int wc = wid;                   // 0..3 : 32-col slice (unique B per wave)
  const int rsub = lane & 15;
  const int sgrp = lane >> 4;

  // A staging: 4 rounds of 256 thr x 16B (32 rows of 128B each), slot-swizzled source
  const int srowA = tid >> 3;
  const int slotA = (tid & 7) ^ (srowA & 7);
  const char* gAbase = A8 + (size_t)(arow0 + srowA) * KDIM + slotA * 16;

  auto stageA = [&](int Adst, int kt) {
#pragma unroll
    for (int rr = 0; rr < 4; ++rr) {
      __builtin_amdgcn_global_load_lds(
          (glob_char*)(gAbase + (size_t)rr * 32 * KDIM + kt * BK),
          (lds_char*)(lds + Adst + rr * 4096 + wid * 1024), 16, 0, 0);
    }
  };

  // per-lane B base in the KT-tiled layout:
  // addr = nt*131072 + kt*4096 + (wc*32 + n*16 + rsub)*32 + (ks*4+sgrp)*4
  const char* gB = (const char*)B3 + (size_t)nt * 131072
                 + (wc * 32 + rsub) * 32 + sgrp * 4;

  // loop-invariant A fragment byte-offsets
  int offA[8][2];
#pragma unroll
  for (int m = 0; m < 8; ++m) {
    const int row = m * 16 + rsub;
#pragma unroll
    for (int ks = 0; ks < 2; ++ks) {
      const int p = (ks * 4 + sgrp) ^ (row & 7);
      offA[m][ks] = row * 128 + p * 16;
    }
  }

  i32x4 acc[8][2];
#pragma unroll
  for (int m = 0; m < 8; ++m)
#pragma unroll
    for (int n = 0; n < 2; ++n)
      acc[m][n] = (i32x4){0, 0, 0, 0};

  // B register double-buffer (named scalars: rule 20). u* = even-t, v* = odd-t.
  unsigned u0, u1, u2, u3, v0, v1, v2, v3;

  // prologue: A(0)->A0 lds; B(0)->u; B(1)->v. Issue order A,u,v ->
  // vmcnt(4) retires A(0)+u, leaves v in flight.
  stageA(A0_OFF, 0);
  u0 = *(const unsigned*)(gB);
  u1 = *(const unsigned*)(gB + 512);
  u2 = *(const unsigned*)(gB + 16);
  u3 = *(const unsigned*)(gB + 528);
  v0 = *(const unsigned*)(gB + 4096);
  v1 = *(const unsigned*)(gB + 4096 + 512);
  v2 = *(const unsigned*)(gB + 4096 + 16);
  v3 = *(const unsigned*)(gB + 4096 + 528);
  asm volatile("s_waitcnt vmcnt(4)" ::: "memory");
  __builtin_amdgcn_s_barrier();

  // one K-step: stage A(t+1); dec2 B(t) from c*; reload c* with B(t+2);
  // 2 ks-blocks of {8 ds_read + 16 MFMA}; vmcnt(4) retires {B(t+1),A(t+1)};
  // barrier. (c* = u* for even t, v* for odd t.)
  auto step = [&](int Acur, int Anxt,
                  unsigned& c0, unsigned& c1, unsigned& c2, unsigned& c3, int t) {
    const int ktA = (t + 1 < NT) ? t + 1 : NT - 1;
    const int ktB = (t + 2 < NT) ? t + 2 : NT - 1;
    stageA(Anxt, ktA);

    i32x4 b00 = dec2(c0);   // n0 ks0
    i32x4 b10 = dec2(c1);   // n1 ks0
    i32x4 b01 = dec2(c2);   // n0 ks1
    i32x4 b11 = dec2(c3);   // n1 ks1

    const char* gBt = gB + (size_t)ktB * 4096;
    c0 = *(const unsigned*)(gBt);
    c1 = *(const unsigned*)(gBt + 512);
    c2 = *(const unsigned*)(gBt + 16);
    c3 = *(const unsigned*)(gBt + 528);

    // ks = 0
    {
      i32x4 a0 = *(const i32x4*)(lds + Acur + offA[0][0]);
      i32x4 a1 = *(const i32x4*)(lds + Acur + offA[1][0]);
      i32x4 a2 = *(const i32x4*)(lds + Acur + offA[2][0]);
      i32x4 a3 = *(const i32x4*)(lds + Acur + offA[3][0]);
      i32x4 a4 = *(const i32x4*)(lds + Acur + offA[4][0]);
      i32x4 a5 = *(const i32x4*)(lds + Acur + offA[5][0]);
      i32x4 a6 = *(const i32x4*)(lds + Acur + offA[6][0]);
      i32x4 a7 = *(const i32x4*)(lds + Acur + offA[7][0]);
      __builtin_amdgcn_s_setprio(1);
      acc[0][0] = __builtin_amdgcn_mfma_i32_16x16x64_i8(a0, b00, acc[0][0], 0, 0, 0);
      acc[1][0] = __builtin_amdgcn_mfma_i32_16x16x64_i8(a1, b00, acc[1][0], 0, 0, 0);
      acc[2][0] = __builtin_amdgcn_mfma_i32_16x16x64_i8(a2, b00, acc[2][0], 0, 0, 0);
      acc[3][0] = __builtin_amdgcn_mfma_i32_16x16x64_i8(a3, b00, acc[3][0], 0, 0, 0);
      acc[4][0] = __builtin_amdgcn_mfma_i32_16x16x64_i8(a4, b00, acc[4][0], 0, 0, 0);
      acc[5][0] = __builtin_amdgcn_mfma_i32_16x16x64_i8(a5, b00, acc[5][0], 0, 0, 0);
      acc[6][0] = __builtin_amdgcn_mfma_i32_16x16x64_i8(a6, b00, acc[6][0], 0, 0, 0);
      acc[7][0] = __builtin_amdgcn_mfma_i32_16x16x64_i8(a7, b00, acc[7][0], 0, 0, 0);
      acc[0][1] = __builtin_amdgcn_mfma_i32_16x16x64_i8(a0, b10, acc[0][1], 0, 0, 0);
      acc[1][1] = __builtin_amdgcn_mfma_i32_16x16x64_i8(a1, b10, acc[1][1], 0, 0, 0);
      acc[2][1] = __builtin_amdgcn_mfma_i32_16x16x64_i8(a2, b10, acc[2][1], 0, 0, 0);
      acc[3][1] = __builtin_amdgcn_mfma_i32_16x16x64_i8(a3, b10, acc[3][1], 0, 0, 0);
      acc[4][1] = __builtin_amdgcn_mfma_i32_16x16x64_i8(a4, b10, acc[4][1], 0, 0, 0);
      acc[5][1] = __builtin_amdgcn_mfma_i32_16x16x64_i8(a5, b10, acc[5][1], 0, 0, 0);
      acc[6][1] = __builtin_amdgcn_mfma_i32_16x16x64_i8(a6, b10, acc[6][1], 0, 0, 0);
      acc[7][1] = __builtin_amdgcn_mfma_i32_16x16x64_i8(a7, b10, acc[7][1], 0, 0, 0);
      __builtin_amdgcn_s_setprio(0);
    }
    // ks = 1
    {
      i32x4 a0 = *(const i32x4*)(lds + Acur + offA[0][1]);
      i32x4 a1 = *(const i32x4*)(lds + Acur + offA[1][1]);
      i32x4 a2 = *(const i32x4*)(lds + Acur + offA[2][1]);
      i32x4 a3 = *(const i32x4*)(lds + Acur + offA[3][1]);
      i32x4 a4 = *(const i32x4*)(lds + Acur + offA[4][1]);
      i32x4 a5 = *(const i32x4*)(lds + Acur + offA[5][1]);
      i32x4 a6 = *(const i32x4*)(lds + Acur + offA[6][1]);
      i32x4 a7 = *(const i32x4*)(lds + Acur + offA[7][1]);
      __builtin_amdgcn_s_setprio(1);
      acc[0][0] = __builtin_amdgcn_mfma_i32_16x16x64_i8(a0, b01, acc[0][0], 0, 0, 0);
      acc[1][0] = __builtin_amdgcn_mfma_i32_16x16x64_i8(a1, b01, acc[1][0], 0, 0, 0);
      acc[2][0] = __builtin_amdgcn_mfma_i32_16x16x64_i8(a2, b01, acc[2][0], 0, 0, 0);
      acc[3][0] = __builtin_amdgcn_mfma_i32_16x16x64_i8(a3, b01, acc[3][0], 0, 0, 0);
      acc[4][0] = __builtin_amdgcn_mfma_i32_16x16x64_i8(a4, b01, acc[4][0], 0, 0, 0);
      acc[5][0] = __builtin_amdgcn_mfma_i32_16x16x64_i8(a5, b01, acc[5][0], 0, 0, 0);
      acc[6][0] = __builtin_amdgcn_mfma_i32_16x16x64_i8(a6, b01, acc[6][0], 0, 0, 0);
      acc[7][0] = __builtin_amdgcn_mfma_i32_16x16x64_i8(a7, b01, acc[7][0], 0, 0, 0);
      acc[0][1] = __builtin_amdgcn_mfma_i32_16x16x64_i8(a0, b11, acc[0][1], 0, 0, 0);
      acc[1][1] = __builtin_amdgcn_mfma_i32_16x16x64_i8(a1, b11, acc[1][1], 0, 0, 0);
      acc[2][1] = __builtin_amdgcn_mfma_i32_16x16x64_i8(a2, b11, acc[2][1], 0, 0, 0);
      acc[3][1] = __builtin_amdgcn_mfma_i32_16x16x64_i8(a3, b11, acc[3][1], 0, 0, 0);
      acc[4][1] = __builtin_amdgcn_mfma_i32_16x16x64_i8(a4, b11, acc[4][1], 0, 0, 0);
      acc[5][1] = __builtin_amdgcn_mfma_i32_16x16x64_i8(a5, b11, acc[5][1], 0, 0, 0);
      acc[6][1] = __builtin_amdgcn_mfma_i32_16x16x64_i8(a6, b11, acc[6][1], 0, 0, 0);
      acc[7][1] = __builtin_amdgcn_mfma_i32_16x16x64_i8(a7, b11, acc[7][1], 0, 0, 0);
      __builtin_amdgcn_s_setprio(0);
    }

    asm volatile("s_waitcnt vmcnt(4)" ::: "memory");
    __builtin_amdgcn_s_barrier();
  };

  for (int t2 = 0; t2 < NT; t2 += 2) {
    step(A0_OFF, A1_OFF, u0, u1, u2, u3, t2);
    step(A1_OFF, A0_OFF, v0, v1, v2, v3, t2 + 1);
  }

  // Epilogue (validated R1-R17): C/D col = lane&15, row = (lane>>4)*4 + reg
  const int crow = sgrp * 4;
#pragma unroll
  for (int n = 0; n < 2; ++n) {
    const int col = brow0 + wc * 32 + n * 16 + rsub;
    const float sc = scale[col];
    const float bs = bias[col];
#pragma unroll
    for (int m = 0; m < 8; ++m) {
      const int r0 = arow0 + m * 16 + crow;
#pragma unroll
      for (int j = 0; j < 4; ++j) {
        out[(size_t)(r0 + j) * NDIM + col] = (float)acc[m][n][j] * sc + bs;
      }
    }
  }
}

extern "C" void kernel_launch(void* const* d_in, const int* in_sizes, int n_in,
                              void* d_out, int out_size, void* d_ws, size_t ws_size,
                              hipStream_t stream) {
  const int*   input  = (const int*)d_in[0];     // [2048][4096] int32
  const int*   weight = (const int*)d_in[1];     // [11008][4096] int32 in {-1,0,1}
  const float* scale  = (const float*)d_in[2];   // [11008]
  const float* bias   = (const float*)d_in[3];   // [11008]
  float*       out    = (float*)d_out;           // [2048][11008] fp32

  const size_t needA = (size_t)BATCH * KDIM;          // 8 MB int8

  char*     A8  = (char*)d_ws;
  unsigned* Bpk = (unsigned*)(A8 + needA);            // 11 MB 2-bit packed, KT-tiled
  const int nA4 = (int)(needA / 4);
  convert_i32_i8<<<(nA4 + 255) / 256, 256, 0, stream>>>(input, (unsigned*)A8, nA4);
  convert_w2<<<NDIM * (KDIM / 16) / 256, 256, 0, stream>>>(weight, Bpk);

  const dim3 grid((BATCH / BM) * (NDIM / BN));   // 16 * 86 = 1376
  const dim3 block(256);
  ternary_gemm<<<grid, block, 0, stream>>>(A8, Bpk, scale, bias, out);
  (void)ws_size; (void)n_in; (void)in_sizes; (void)out_size;
}

// Round 19
// 138.169 us; speedup vs baseline: 1.2583x; 1.2583x over previous
//
#include <hip/hip_runtime.h>
#include <stdint.h>

#define BATCH   2048
#define KDIM    4096
#define NDIM    11008

#define BM 128
#define BN 128
#define BK 128
#define NT (KDIM / BK)               // 32 K-tiles
#define BPK_ROWB 1024                // packed B row bytes = KDIM/4

// LDS map: A dbuf 2x16KB at 0/16384; B 4-deep 4x4KB at 32768+4096*i; 48KB
#define A0_OFF 0
#define A1_OFF 16384
#define B_BASE 32768

typedef __attribute__((ext_vector_type(4))) int i32x4;

typedef const __attribute__((address_space(1))) char glob_char;
typedef __attribute__((address_space(3))) char lds_char;

__device__ __forceinline__ unsigned pack4(i32x4 v) {
  return  ((unsigned)v.x & 0xFFu)
        | (((unsigned)v.y & 0xFFu) << 8)
        | (((unsigned)v.z & 0xFFu) << 16)
        | (((unsigned)v.w)         << 24);
}

// A: int32 (values in [-128,127]) -> packed int8, 4 elements per thread
__global__ __launch_bounds__(256) void convert_i32_i8(const int* __restrict__ src,
                                                      unsigned* __restrict__ dst,
                                                      int n4) {
  int idx = blockIdx.x * 256 + threadIdx.x;
  if (idx >= n4) return;
  i32x4 v = ((const i32x4*)src)[idx];
  dst[idx] = pack4(v);
}

// B: ternary int32 -> 2-bit packed (R12-R17-validated layout). Element e of
// word at bits [8*(e&3) + 2*(e>>2)]; LDS bank swizzle baked in: word i%8
// stored at slot (i%8)^(row&7) within its 32B group.
// R20: VECTORIZED source reads (4 x i32x4 = 4 VMEM ops/thread instead of 16
// scalar dwords) -> convert runs at its 28-29us HBM floor.
__global__ __launch_bounds__(256) void convert_w2(const int* __restrict__ src,
                                                  unsigned* __restrict__ dst) {
  const int f = blockIdx.x * 256 + threadIdx.x;   // < 11008*256
  const int r = f >> 8;                           // row 0..11007
  const int i = f & 255;                          // word-in-row 0..255
  const i32x4* p = (const i32x4*)(src + (size_t)r * KDIM + i * 16);
  i32x4 q0 = p[0];
  i32x4 q1 = p[1];
  i32x4 q2 = p[2];
  i32x4 q3 = p[3];
  // element e = q[e>>2][e&3]; bit position 8*(e&3) + 2*(e>>2)
  unsigned w = 0;
#pragma unroll
  for (int c = 0; c < 4; ++c) {                   // c = e&3 (byte)
#pragma unroll
    for (int g = 0; g < 4; ++g) {                 // g within nibble-pair group
      // e = (g + c*0) ... map: for byte c, the four elements are e = c, 4+c, 8+c, 12+c
      // which live in q[(4g+c)>>2][(4g+c)&3] = q[g][c]
      const i32x4& qq = (g == 0) ? q0 : (g == 1) ? q1 : (g == 2) ? q2 : q3;
      const unsigned v = (unsigned)qq[c] & 3u;
      w |= v << (8 * c + 2 * g);
    }
  }
  const int slot = (i & 7) ^ (r & 7);
  dst[(size_t)r * 256 + (i >> 3) * 8 + slot] = w;
}

// decode 16x 2-bit ternary -> 16 int8 (k-order): (x&M1) | ((y<<7)-y), y=x&M2
__device__ __forceinline__ i32x4 dec2(unsigned w) {
  const unsigned M1 = 0x01010101u, M2 = 0x02020202u;
  i32x4 r;
  { unsigned x = w;      unsigned y = x & M2; r.x = (int)((x & M1) | ((y << 7) - y)); }
  { unsigned x = w >> 2; unsigned y = x & M2; r.y = (int)((x & M1) | ((y << 7) - y)); }
  { unsigned x = w >> 4; unsigned y = x & M2; r.z = (int)((x & M1) | ((y << 7) - y)); }
  { unsigned x = w >> 6; unsigned y = x & M2; r.w = (int)((x & M1) | ((y << 7) - y)); }
  return r;
}

// C[2048][11008] = A[2048][4096] * W[11008][4096]^T via mfma_i32_16x16x64_i8.
// R20 = R14 EXACT REVERT (measured best: 138.2us total, GEMM ~98us):
//  - 1m x 4n wave grid (wave 128x32), 2-bit B, unique-per-wave decode.
//  - A depth-1 dbuf (L2-resident panel), B depth-2 over 4 x 4KB buffers;
//    per KT: issue A(t+1)x4 then B(t+2); ONE counted vmcnt(1) retires
//    {B(t+1), A(t+1)x4}, leaves B(t+2) in flight.
//  - x4-unrolled loop -> compile-time LDS offsets; no manual lgkmcnt/
//    sched_barrier (R6 lesson); 48KB LDS -> 3 blocks/CU; acc 64 AGPR.
//  - Design-space conclusion (R12-R19): eff = steady x tail is ~1850 TOPS
//    at BOTH reachable corners (wave_n=64: 2687x0.67; wave_n=32: 2104x0.896)
//    - this structure sits at the better corner; B-in-reg (R19) and 2-wave
//    blocks (R17) both regressed.
__global__ __launch_bounds__(256, 3) void ternary_gemm(const char* __restrict__ A8,
                                                       const unsigned* __restrict__ B2,
                                                       const float* __restrict__ scale,
                                                       const float* __restrict__ bias,
                                                       float* __restrict__ out) {
  __shared__ char lds[49152];          // 48KB -> 3 blocks/CU

  const int tid  = threadIdx.x;
  const int wid  = tid >> 6;
  const int lane = tid & 63;

  // XCD swizzle (1376 % 8 == 0 -> bijective) + 4-wide mt-supertile raster
  const int wg  = (blockIdx.x & 7) * 172 + (blockIdx.x >> 3);
  const int mtq = wg / 344;
  const int r   = wg - mtq * 344;
  const int nt  = r >> 2;
  const int mt  = mtq * 4 + (r & 3);
  const int arow0 = mt * BM;
  const int brow0 = nt * BN;

  const int wc = wid;                  // 0..3 : 32-col slice (unique B per wave)
  const int rsub = lane & 15;
  const int sgrp = lane >> 4;

  // A staging: 4 rounds of 256 thr x 16B (32 rows of 128B each)
  const int srowA = tid >> 3;
  const int slotA = (tid & 7) ^ (srowA & 7);
  // B staging: 1 round of 256 thr x 16B (128 rows of 32B), linear copy
  const int srowB = tid >> 1;
  const int shalfB = (tid & 1) * 16;

  const char* gAbase = A8 + (size_t)(arow0 + srowA) * KDIM + slotA * 16;
  const char* gBbase = (const char*)B2 + (size_t)(brow0 + srowB) * BPK_ROWB + shalfB;

  auto stageA = [&](int Adst, int kt) {
#pragma unroll
    for (int rr = 0; rr < 4; ++rr) {
      __builtin_amdgcn_global_load_lds(
          (glob_char*)(gAbase + (size_t)rr * 32 * KDIM + kt * BK),
          (lds_char*)(lds + Adst + rr * 4096 + wid * 1024), 16, 0, 0);
    }
  };
  auto stageB = [&](int Bdst, int kt) {
    __builtin_amdgcn_global_load_lds(
        (glob_char*)(gBbase + kt * (BK / 4)),
        (lds_char*)(lds + Bdst + wid * 1024), 16, 0, 0);
  };

  // loop-invariant fragment byte-offsets (buffer-relative)
  int offA[8][2], offB[2][2];
#pragma unroll
  for (int m = 0; m < 8; ++m) {
    const int row = m * 16 + rsub;
#pragma unroll
    for (int ks = 0; ks < 2; ++ks) {
      const int p = (ks * 4 + sgrp) ^ (row & 7);
      offA[m][ks] = row * 128 + p * 16;
    }
  }
#pragma unroll
  for (int n = 0; n < 2; ++n) {
    const int row = wc * 32 + n * 16 + rsub;
#pragma unroll
    for (int ks = 0; ks < 2; ++ks) {
      const int p = (ks * 4 + sgrp) ^ (row & 7);
      offB[n][ks] = row * 32 + p * 4;
    }
  }

  i32x4 acc[8][2];
#pragma unroll
  for (int m = 0; m < 8; ++m)
#pragma unroll
    for (int n = 0; n < 2; ++n)
      acc[m][n] = (i32x4){0, 0, 0, 0};

  // prologue: A(0)->A0, B(0)->B0, B(1)->B1; full drain once
  stageA(A0_OFF, 0);
  stageB(B_BASE, 0);
  stageB(B_BASE + 4096, 1);
  asm volatile("s_waitcnt vmcnt(0)" ::: "memory");
  __builtin_amdgcn_s_barrier();

  // one K-step: stage A(t+1)->Anxt, B(t+2)->Bpf; compute from Acur/Bcur;
  // vmcnt(1) retires {B(t+1), A(t+1)x4}, leaves B(t+2) in flight; barrier.
  auto step = [&](int Acur, int Anxt, int Bcur, int Bpf, int t) {
    const int ktA = (t + 1 < NT) ? t + 1 : NT - 1;
    const int ktB = (t + 2 < NT) ? t + 2 : NT - 1;
    stageA(Anxt, ktA);
    stageB(Bpf, ktB);
#pragma unroll
    for (int ks = 0; ks < 2; ++ks) {
      i32x4 a0 = *(const i32x4*)(lds + Acur + offA[0][ks]);
      i32x4 a1 = *(const i32x4*)(lds + Acur + offA[1][ks]);
      i32x4 a2 = *(const i32x4*)(lds + Acur + offA[2][ks]);
      i32x4 a3 = *(const i32x4*)(lds + Acur + offA[3][ks]);
      i32x4 a4 = *(const i32x4*)(lds + Acur + offA[4][ks]);
      i32x4 a5 = *(const i32x4*)(lds + Acur + offA[5][ks]);
      i32x4 a6 = *(const i32x4*)(lds + Acur + offA[6][ks]);
      i32x4 a7 = *(const i32x4*)(lds + Acur + offA[7][ks]);
      unsigned w0 = *(const unsigned*)(lds + Bcur + offB[0][ks]);
      unsigned w1 = *(const unsigned*)(lds + Bcur + offB[1][ks]);
      i32x4 b0 = dec2(w0);
      i32x4 b1 = dec2(w1);
      __builtin_amdgcn_s_setprio(1);
      acc[0][0] = __builtin_amdgcn_mfma_i32_16x16x64_i8(a0, b0, acc[0][0], 0, 0, 0);
      acc[1][0] = __builtin_amdgcn_mfma_i32_16x16x64_i8(a1, b0, acc[1][0], 0, 0, 0);
      acc[2][0] = __builtin_amdgcn_mfma_i32_16x16x64_i8(a2, b0, acc[2][0], 0, 0, 0);
      acc[3][0] = __builtin_amdgcn_mfma_i32_16x16x64_i8(a3, b0, acc[3][0], 0, 0, 0);
      acc[4][0] = __builtin_amdgcn_mfma_i32_16x16x64_i8(a4, b0, acc[4][0], 0, 0, 0);
      acc[5][0] = __builtin_amdgcn_mfma_i32_16x16x64_i8(a5, b0, acc[5][0], 0, 0, 0);
      acc[6][0] = __builtin_amdgcn_mfma_i32_16x16x64_i8(a6, b0, acc[6][0], 0, 0, 0);
      acc[7][0] = __builtin_amdgcn_mfma_i32_16x16x64_i8(a7, b0, acc[7][0], 0, 0, 0);
      acc[0][1] = __builtin_amdgcn_mfma_i32_16x16x64_i8(a0, b1, acc[0][1], 0, 0, 0);
      acc[1][1] = __builtin_amdgcn_mfma_i32_16x16x64_i8(a1, b1, acc[1][1], 0, 0, 0);
      acc[2][1] = __builtin_amdgcn_mfma_i32_16x16x64_i8(a2, b1, acc[2][1], 0, 0, 0);
      acc[3][1] = __builtin_amdgcn_mfma_i32_16x16x64_i8(a3, b1, acc[3][1], 0, 0, 0);
      acc[4][1] = __builtin_amdgcn_mfma_i32_16x16x64_i8(a4, b1, acc[4][1], 0, 0, 0);
      acc[5][1] = __builtin_amdgcn_mfma_i32_16x16x64_i8(a5, b1, acc[5][1], 0, 0, 0);
      acc[6][1] = __builtin_amdgcn_mfma_i32_16x16x64_i8(a6, b1, acc[6][1], 0, 0, 0);
      acc[7][1] = __builtin_amdgcn_mfma_i32_16x16x64_i8(a7, b1, acc[7][1], 0, 0, 0);
      __builtin_amdgcn_s_setprio(0);
    }
    asm volatile("s_waitcnt vmcnt(1)" ::: "memory");
    __builtin_amdgcn_s_barrier();
  };

  for (int t4 = 0; t4 < NT; t4 += 4) {
    step(A0_OFF, A1_OFF, B_BASE,         B_BASE +  8192, t4);
    step(A1_OFF, A0_OFF, B_BASE +  4096, B_BASE + 12288, t4 + 1);
    step(A0_OFF, A1_OFF, B_BASE +  8192, B_BASE,         t4 + 2);
    step(A1_OFF, A0_OFF, B_BASE + 12288, B_BASE +  4096, t4 + 3);
  }

  // Epilogue (validated R1-R19): C/D col = lane&15, row = (lane>>4)*4 + reg
  const int crow = sgrp * 4;
#pragma unroll
  for (int n = 0; n < 2; ++n) {
    const int col = brow0 + wc * 32 + n * 16 + rsub;
    const float sc = scale[col];
    const float bs = bias[col];
#pragma unroll
    for (int m = 0; m < 8; ++m) {
      const int r0 = arow0 + m * 16 + crow;
#pragma unroll
      for (int j = 0; j < 4; ++j) {
        out[(size_t)(r0 + j) * NDIM + col] = (float)acc[m][n][j] * sc + bs;
      }
    }
  }
}

extern "C" void kernel_launch(void* const* d_in, const int* in_sizes, int n_in,
                              void* d_out, int out_size, void* d_ws, size_t ws_size,
                              hipStream_t stream) {
  const int*   input  = (const int*)d_in[0];     // [2048][4096] int32
  const int*   weight = (const int*)d_in[1];     // [11008][4096] int32 in {-1,0,1}
  const float* scale  = (const float*)d_in[2];   // [11008]
  const float* bias   = (const float*)d_in[3];   // [11008]
  float*       out    = (float*)d_out;           // [2048][11008] fp32

  const size_t needA = (size_t)BATCH * KDIM;          // 8 MB int8

  char*     A8  = (char*)d_ws;
  unsigned* Bpk = (unsigned*)(A8 + needA);            // 11 MB 2-bit packed
  const int nA4 = (int)(needA / 4);
  convert_i32_i8<<<(nA4 + 255) / 256, 256, 0, stream>>>(input, (unsigned*)A8, nA4);
  convert_w2<<<NDIM * (KDIM / 16) / 256, 256, 0, stream>>>(weight, Bpk);

  const dim3 grid((BATCH / BM) * (NDIM / BN));   // 16 * 86 = 1376
  const dim3 block(256);
  ternary_gemm<<<grid, block, 0, stream>>>(A8, Bpk, scale, bias, out);
  (void)ws_size; (void)n_in; (void)in_sizes; (void)out_size;
}